// Round 1
// baseline (199.034 us; speedup 1.0000x reference)
//
#include <hip/hip_runtime.h>
#include <math.h>

#define BATCH 65536
#define LHIST 128
#define HFUT  32

__device__ __forceinline__ float softplusf(float x) {
    // log(1+e^x), numerically stable; matches jax.nn.softplus
    return fmaxf(x, 0.0f) + log1pf(expf(-fabsf(x)));
}

__global__ __launch_bounds__(256) void kalman_fwd(
    const float* __restrict__ v_hist,
    const float* __restrict__ dt_hist,
    const float* __restrict__ x_obs,
    const float* __restrict__ v_fut,
    const float* __restrict__ dt_fut,
    const float* __restrict__ theta,
    float* __restrict__ out)
{
    const int b = blockIdx.x * blockDim.x + threadIdx.x;

    // ---- uniform parameter transforms (theta ptr + const idx -> scalar loads) ----
    const float alpha = 1.0f / (1.0f + expf(-theta[0]));
    const float c     = softplusf(theta[1]);
    const float kappa = softplusf(theta[2]);
    const float vc    = softplusf(theta[3]);       // VC_MIN = 0
    const float qx    = expf(theta[4]);
    const float qu    = expf(theta[5]);
    const float Rn    = expf(theta[6]);
    const float qs    = expf(theta[7]);
    const float p0xx  = expf(theta[8]);
    const float p0uu  = expf(theta[9]);
    const float a1    = softplusf(theta[10]);
    const float d1    = softplusf(theta[11]);
    const float d2    = softplusf(theta[12]);
    const float d3    = softplusf(theta[13]);
    const float b1    = theta[14];
    const float b2    = theta[15];
    const float beta  = theta[16];
    const float rho_m = tanhf(theta[17]);
    const float qm    = expf(theta[18]);
    const float p0mm  = expf(theta[19]);
    const float vc2   = vc * vc;
    const float qxs   = qs * qx;
    const float qus   = qs * qu;

    // ---- per-thread state: s = (x,u,m); P symmetric 3x3 (6 uniques) ----
    float sx, su = 0.0f, sm = 0.0f;
    float p00 = p0xx, p01 = 0.0f, p02 = 0.0f, p11 = p0uu, p12 = 0.0f, p22 = p0mm;

    auto predict = [&](float v, float dv, float dt_raw) {
        float dt  = fmaxf(dt_raw, 1e-6f);
        float rho = expf(-alpha * dt);
        float forcing = fmaxf(v * v - vc2, 0.0f);
        float cl = -a1 * su + b1 * v + b2 * dv
                 - d1 * su * su - d2 * su * fabsf(v) - d3 * su * fabsf(su);
        float kdt = kappa * dt;
        float x_p = sx + su * dt;
        float u_p = rho * su - kdt * sx + c * forcing * dt + cl * dt + beta * sm;
        float m_p = rho_m * sm;
        // F = [[1,dt,0],[-kdt,rho,beta],[0,0,rho_m]];  P_p = F P F^T + diag(q)
        float f0 = p00 + dt * p01;               // (FP) row0
        float f1 = p01 + dt * p11;
        float f2 = p02 + dt * p12;
        float g0 = -kdt * p00 + rho * p01 + beta * p02;   // (FP) row1
        float g1 = -kdt * p01 + rho * p11 + beta * p12;
        float g2 = -kdt * p02 + rho * p12 + beta * p22;
        float n00 = f0 + dt * f1 + qxs * dt;
        float n01 = -kdt * f0 + rho * f1 + beta * f2;
        float n02 = rho_m * f2;
        float n11 = -kdt * g0 + rho * g1 + beta * g2 + qus * dt;
        float n12 = rho_m * g2;
        float n22 = rho_m * rho_m * p22 + qm;
        sx = x_p; su = u_p; sm = m_p;
        p00 = n00; p01 = n01; p02 = n02; p11 = n11; p12 = n12; p22 = n22;
    };

    auto update = [&](float y) {
        float innov = y - sx;
        float S    = p00 + Rn;
        float Sinv = __builtin_amdgcn_rcpf(S);   // ~1ulp; filter is contractive
        float K0 = p00 * Sinv, K1 = p01 * Sinv, K2 = p02 * Sinv;
        sx += K0 * innov; su += K1 * innov; sm += K2 * innov;
        // Joseph form, expanded for symmetric P
        float a = 1.0f - K0;
        float n00 = a * a * p00 + Rn * K0 * K0;
        float n01 = a * (p01 - K1 * p00) + Rn * K0 * K1;
        float n02 = a * (p02 - K2 * p00) + Rn * K0 * K2;
        float n11 = S * K1 * K1 - 2.0f * K1 * p01 + p11;
        float n12 = S * K1 * K2 - K2 * p01 - K1 * p02 + p12;
        float n22 = S * K2 * K2 - 2.0f * K2 * p02 + p22;
        p00 = n00; p01 = n01; p02 = n02; p11 = n11; p12 = n12; p22 = n22;
    };

    // ---- history scan: t = 0..126 ----
    // step t: v[t], dv = v[t]-v[t-1] (0 at t=0), dt = dt_hist[t+1], y = x_obs[t+1]
    const float4* v4 = (const float4*)(v_hist  + (size_t)b * LHIST);
    const float4* d4 = (const float4*)(dt_hist + (size_t)b * LHIST);
    const float4* y4 = (const float4*)(x_obs   + (size_t)b * LHIST);

    float4 vq = v4[0], dq = d4[0], yq = y4[0];
    float4 vn = v4[1], dn = d4[1], yn = y4[1];
    sx = yq.x;                      // s0.x = x_obs[b][0]

    // t = 0,1,2 from quad 0 (dt/y elements 1..3)
    predict(vq.x, 0.0f,        dq.y); update(yq.y);
    predict(vq.y, vq.y - vq.x, dq.z); update(yq.z);
    predict(vq.z, vq.z - vq.y, dq.w); update(yq.w);

    #pragma unroll 1
    for (int q = 1; q < 31; ++q) {
        float4 v2 = v4[q + 1], d2 = d4[q + 1], y2 = y4[q + 1];  // prefetch next
        predict(vq.w, vq.w - vq.z, dn.x); update(yn.x);   // t = 4q-1
        predict(vn.x, vn.x - vq.w, dn.y); update(yn.y);   // t = 4q
        predict(vn.y, vn.y - vn.x, dn.z); update(yn.z);   // t = 4q+1
        predict(vn.z, vn.z - vn.y, dn.w); update(yn.w);   // t = 4q+2
        vq = vn; vn = v2; dn = d2; yn = y2;
    }
    // tail: quads 30(vq)/31(vn): t = 123..126
    predict(vq.w, vq.w - vq.z, dn.x); update(yn.x);
    predict(vn.x, vn.x - vq.w, dn.y); update(yn.y);
    predict(vn.y, vn.y - vn.x, dn.z); update(yn.z);
    predict(vn.z, vn.z - vn.y, dn.w); update(yn.w);
    float v_prev = vn.w;            // v_hist[b][127], feeds dv of future step 0

    // ---- future rollout: j = 0..31, predict only, record (x, P00, u) ----
    const float4* vf4 = (const float4*)(v_fut  + (size_t)b * HFUT);
    const float4* df4 = (const float4*)(dt_fut + (size_t)b * HFUT);
    float4* xp = (float4*)(out + (size_t)b * HFUT);
    float4* xv = (float4*)(out + (size_t)BATCH * HFUT + (size_t)b * HFUT);
    float4* ue = (float4*)(out + 2 * (size_t)BATCH * HFUT + (size_t)b * HFUT);

    #pragma unroll 1
    for (int q = 0; q < HFUT / 4; ++q) {
        float4 vf = vf4[q], df = df4[q];
        float4 oxp, oxv, oue;
        predict(vf.x, vf.x - v_prev, df.x); oxp.x = sx; oxv.x = p00; oue.x = su;
        predict(vf.y, vf.y - vf.x,   df.y); oxp.y = sx; oxv.y = p00; oue.y = su;
        predict(vf.z, vf.z - vf.y,   df.z); oxp.z = sx; oxv.z = p00; oue.z = su;
        predict(vf.w, vf.w - vf.z,   df.w); oxp.w = sx; oxv.w = p00; oue.w = su;
        v_prev = vf.w;
        xp[q] = oxp; xv[q] = oxv; ue[q] = oue;
    }
}

extern "C" void kernel_launch(void* const* d_in, const int* in_sizes, int n_in,
                              void* d_out, int out_size, void* d_ws, size_t ws_size,
                              hipStream_t stream) {
    const float* v_hist  = (const float*)d_in[0];
    const float* dt_hist = (const float*)d_in[1];
    const float* x_obs   = (const float*)d_in[2];
    const float* v_fut   = (const float*)d_in[3];
    const float* dt_fut  = (const float*)d_in[4];
    const float* theta   = (const float*)d_in[5];
    float* out = (float*)d_out;

    dim3 grid(BATCH / 256), block(256);
    hipLaunchKernelGGL(kalman_fwd, grid, block, 0, stream,
                       v_hist, dt_hist, x_obs, v_fut, dt_fut, theta, out);
}

// Round 2
// 186.868 us; speedup vs baseline: 1.0651x; 1.0651x over previous
//
#include <hip/hip_runtime.h>
#include <math.h>

#define BATCH 65536
#define LHIST 128
#define HFUT  32

__device__ __forceinline__ float softplusf(float x) {
    // log(1+e^x), numerically stable; matches jax.nn.softplus
    return fmaxf(x, 0.0f) + log1pf(expf(-fabsf(x)));
}

// 1 wave/SIMD occupancy anyway (65536 threads / 256 CUs) -> allow big VGPR use
__global__ __launch_bounds__(256, 1) void kalman_fwd(
    const float* __restrict__ v_hist,
    const float* __restrict__ dt_hist,
    const float* __restrict__ x_obs,
    const float* __restrict__ v_fut,
    const float* __restrict__ dt_fut,
    const float* __restrict__ theta,
    float* __restrict__ out)
{
    const int b = blockIdx.x * blockDim.x + threadIdx.x;

    // ---- uniform parameter transforms ----
    const float alpha = 1.0f / (1.0f + expf(-theta[0]));
    const float c     = softplusf(theta[1]);
    const float kappa = softplusf(theta[2]);
    const float vc    = softplusf(theta[3]);       // VC_MIN = 0
    const float qx    = expf(theta[4]);
    const float qu    = expf(theta[5]);
    const float Rn    = expf(theta[6]);
    const float qs    = expf(theta[7]);
    const float p0xx  = expf(theta[8]);
    const float p0uu  = expf(theta[9]);
    const float a1    = softplusf(theta[10]);
    const float d1    = softplusf(theta[11]);
    const float d2    = softplusf(theta[12]);
    const float d3    = softplusf(theta[13]);
    const float b1    = theta[14];
    const float b2    = theta[15];
    const float beta  = theta[16];
    const float rho_m = tanhf(theta[17]);
    const float qm    = expf(theta[18]);
    const float p0mm  = expf(theta[19]);
    const float vc2   = vc * vc;
    const float qxs   = qs * qx;
    const float qus   = qs * qu;

    // ---- per-thread state: s = (x,u,m); P symmetric 3x3 (6 uniques) ----
    float sx = 0.0f, su = 0.0f, sm = 0.0f;
    float p00 = p0xx, p01 = 0.0f, p02 = 0.0f, p11 = p0uu, p12 = 0.0f, p22 = p0mm;

    auto predict = [&](float v, float dv, float dt_raw) {
        float dt  = fmaxf(dt_raw, 1e-6f);
        float rho = expf(-alpha * dt);
        float forcing = fmaxf(v * v - vc2, 0.0f);
        float cl = -a1 * su + b1 * v + b2 * dv
                 - d1 * su * su - d2 * su * fabsf(v) - d3 * su * fabsf(su);
        float kdt = kappa * dt;
        float x_p = sx + su * dt;
        float u_p = rho * su - kdt * sx + c * forcing * dt + cl * dt + beta * sm;
        float m_p = rho_m * sm;
        // F = [[1,dt,0],[-kdt,rho,beta],[0,0,rho_m]];  P_p = F P F^T + diag(q)
        float f0 = p00 + dt * p01;
        float f1 = p01 + dt * p11;
        float f2 = p02 + dt * p12;
        float g0 = -kdt * p00 + rho * p01 + beta * p02;
        float g1 = -kdt * p01 + rho * p11 + beta * p12;
        float g2 = -kdt * p02 + rho * p12 + beta * p22;
        float n00 = f0 + dt * f1 + qxs * dt;
        float n01 = -kdt * f0 + rho * f1 + beta * f2;
        float n02 = rho_m * f2;
        float n11 = -kdt * g0 + rho * g1 + beta * g2 + qus * dt;
        float n12 = rho_m * g2;
        float n22 = rho_m * rho_m * p22 + qm;
        sx = x_p; su = u_p; sm = m_p;
        p00 = n00; p01 = n01; p02 = n02; p11 = n11; p12 = n12; p22 = n22;
    };

    auto update = [&](float y) {
        float innov = y - sx;
        float S    = p00 + Rn;
        float Sinv = __builtin_amdgcn_rcpf(S);
        float K0 = p00 * Sinv, K1 = p01 * Sinv, K2 = p02 * Sinv;
        sx += K0 * innov; su += K1 * innov; sm += K2 * innov;
        float a = 1.0f - K0;
        float n00 = a * a * p00 + Rn * K0 * K0;
        float n01 = a * (p01 - K1 * p00) + Rn * K0 * K1;
        float n02 = a * (p02 - K2 * p00) + Rn * K0 * K2;
        float n11 = S * K1 * K1 - 2.0f * K1 * p01 + p11;
        float n12 = S * K1 * K2 - K2 * p01 - K1 * p02 + p12;
        float n22 = S * K2 * K2 - 2.0f * K2 * p02 + p22;
        p00 = n00; p01 = n01; p02 = n02; p11 = n11; p12 = n12; p22 = n22;
    };

    const float4* v4  = (const float4*)(v_hist  + (size_t)b * LHIST);
    const float4* d4  = (const float4*)(dt_hist + (size_t)b * LHIST);
    const float4* y4  = (const float4*)(x_obs   + (size_t)b * LHIST);
    const float4* vf4 = (const float4*)(v_fut   + (size_t)b * HFUT);
    const float4* df4 = (const float4*)(dt_fut  + (size_t)b * HFUT);

    // ---- preload future inputs (whole lines; consumed last, latency hidden) ----
    float vf[HFUT], df[HFUT];
    {
        float4* VF = (float4*)vf; float4* DF = (float4*)df;
        #pragma unroll
        for (int i = 0; i < HFUT / 4; ++i) { VF[i] = vf4[i]; DF[i] = df4[i]; }
    }

    // ---- history scan: 4 chunks x 32 time steps, full-line register staging ----
    // step t: v[t], dv = v[t]-v[t-1] (0 at t=0), dt = dt_hist[t+1], y = x_obs[t+1]
    // chunk k>=1 completes steps t = 32k-1 .. 32k+30; chunk 0: t = 0..30.
    float v_bridge = 0.0f, dv_bridge = 0.0f;

    #pragma unroll 1
    for (int k = 0; k < 4; ++k) {
        float vv[32], dd[32], yy[32];
        float4* V = (float4*)vv; float4* D = (float4*)dd; float4* Y = (float4*)yy;
        #pragma unroll
        for (int i = 0; i < 8; ++i) {   // 24 dwordx4 loads in flight, 1 line/array
            V[i] = v4[8 * k + i];
            D[i] = d4[8 * k + i];
            Y[i] = y4[8 * k + i];
        }
        if (k == 0) {
            sx = yy[0];                                   // s0.x = x_obs[b][0]
            predict(vv[0], 0.0f, dd[1]); update(yy[1]);   // t = 0
        } else {
            predict(v_bridge, dv_bridge, dd[0]); update(yy[0]);        // t = 32k-1
            predict(vv[0], vv[0] - v_bridge, dd[1]); update(yy[1]);    // t = 32k
        }
        #pragma unroll
        for (int i = 1; i < 31; ++i) {                    // t = 32k+i
            predict(vv[i], vv[i] - vv[i - 1], dd[i + 1]); update(yy[i + 1]);
        }
        v_bridge  = vv[31];
        dv_bridge = vv[31] - vv[30];
    }
    // after k=3: steps 0..126 done; v_bridge = v_hist[b][127]

    // ---- future rollout: 32 predicts, outputs staged in registers ----
    float oxp[HFUT], oxv[HFUT], oue[HFUT];
    float vp = v_bridge;
    #pragma unroll
    for (int j = 0; j < HFUT; ++j) {
        predict(vf[j], vf[j] - vp, df[j]);
        vp = vf[j];
        oxp[j] = sx; oxv[j] = p00; oue[j] = su;
    }

    // ---- back-to-back full-line stores ----
    float4* xp = (float4*)(out + (size_t)b * HFUT);
    float4* xv = (float4*)(out + (size_t)BATCH * HFUT + (size_t)b * HFUT);
    float4* ue = (float4*)(out + 2 * (size_t)BATCH * HFUT + (size_t)b * HFUT);
    float4* OXP = (float4*)oxp; float4* OXV = (float4*)oxv; float4* OUE = (float4*)oue;
    #pragma unroll
    for (int i = 0; i < HFUT / 4; ++i) {
        xp[i] = OXP[i]; xv[i] = OXV[i]; ue[i] = OUE[i];
    }
}

extern "C" void kernel_launch(void* const* d_in, const int* in_sizes, int n_in,
                              void* d_out, int out_size, void* d_ws, size_t ws_size,
                              hipStream_t stream) {
    const float* v_hist  = (const float*)d_in[0];
    const float* dt_hist = (const float*)d_in[1];
    const float* x_obs   = (const float*)d_in[2];
    const float* v_fut   = (const float*)d_in[3];
    const float* dt_fut  = (const float*)d_in[4];
    const float* theta   = (const float*)d_in[5];
    float* out = (float*)d_out;

    dim3 grid(BATCH / 256), block(256);
    hipLaunchKernelGGL(kalman_fwd, grid, block, 0, stream,
                       v_hist, dt_hist, x_obs, v_fut, dt_fut, theta, out);
}

// Round 3
// 162.226 us; speedup vs baseline: 1.2269x; 1.1519x over previous
//
#include <hip/hip_runtime.h>
#include <math.h>

#define BATCH 65536
#define LHIST 128
#define HFUT  32
#define CH    16          // history chunk length (steps staged per load burst)

__device__ __forceinline__ float softplusf(float x) {
    // log(1+e^x), numerically stable; matches jax.nn.softplus (uniform, runs once)
    return fmaxf(x, 0.0f) + log1pf(expf(-fabsf(x)));
}

// 65536 threads / (256 CU x 4 SIMD) = exactly 1 wave/SIMD regardless of VGPRs
__global__ __launch_bounds__(256, 1) void kalman_fwd(
    const float* __restrict__ v_hist,
    const float* __restrict__ dt_hist,
    const float* __restrict__ x_obs,
    const float* __restrict__ v_fut,
    const float* __restrict__ dt_fut,
    const float* __restrict__ theta,
    float* __restrict__ out)
{
    const int b = blockIdx.x * blockDim.x + threadIdx.x;

    // ---- uniform parameter transforms (once per thread, wave-uniform) ----
    const float alpha = 1.0f / (1.0f + expf(-theta[0]));
    const float c     = softplusf(theta[1]);
    const float kappa = softplusf(theta[2]);
    const float vc    = softplusf(theta[3]);       // VC_MIN = 0
    const float qx    = expf(theta[4]);
    const float qu    = expf(theta[5]);
    const float Rn    = expf(theta[6]);
    const float qs    = expf(theta[7]);
    const float p0xx  = expf(theta[8]);
    const float p0uu  = expf(theta[9]);
    const float a1    = softplusf(theta[10]);
    const float d1    = softplusf(theta[11]);
    const float d2    = softplusf(theta[12]);
    const float d3    = softplusf(theta[13]);
    const float b1    = theta[14];
    const float b2    = theta[15];
    const float beta  = theta[16];
    const float rho_m = tanhf(theta[17]);
    const float qm    = expf(theta[18]);
    const float p0mm  = expf(theta[19]);
    const float vc2   = vc * vc;
    const float qxs   = qs * qx;
    const float qus   = qs * qu;
    // exp(-alpha*dt) = exp2(nal2e*dt): 1 mul + 1 v_exp_f32 (vs libm expf call)
    const float nal2e = -alpha * 1.44269504088896340736f;

    // ---- per-thread state: s = (x,u,m); P symmetric 3x3 (6 uniques) ----
    float sx = 0.0f, su = 0.0f, sm = 0.0f;
    float p00 = p0xx, p01 = 0.0f, p02 = 0.0f, p11 = p0uu, p12 = 0.0f, p22 = p0mm;

    auto predict = [&](float v, float dv, float dt_raw) {
        float dt  = fmaxf(dt_raw, 1e-6f);
        float rho = __builtin_amdgcn_exp2f(nal2e * dt);
        float forcing = fmaxf(v * v - vc2, 0.0f);
        float cl = -a1 * su + b1 * v + b2 * dv
                 - d1 * su * su - d2 * su * fabsf(v) - d3 * su * fabsf(su);
        float kdt = kappa * dt;
        float x_p = sx + su * dt;
        float u_p = rho * su - kdt * sx + c * forcing * dt + cl * dt + beta * sm;
        float m_p = rho_m * sm;
        // F = [[1,dt,0],[-kdt,rho,beta],[0,0,rho_m]];  P_p = F P F^T + diag(q)
        float f0 = p00 + dt * p01;
        float f1 = p01 + dt * p11;
        float f2 = p02 + dt * p12;
        float g0 = -kdt * p00 + rho * p01 + beta * p02;
        float g1 = -kdt * p01 + rho * p11 + beta * p12;
        float g2 = -kdt * p02 + rho * p12 + beta * p22;
        float n00 = f0 + dt * f1 + qxs * dt;
        float n01 = -kdt * f0 + rho * f1 + beta * f2;
        float n02 = rho_m * f2;
        float n11 = -kdt * g0 + rho * g1 + beta * g2 + qus * dt;
        float n12 = rho_m * g2;
        float n22 = rho_m * rho_m * p22 + qm;
        sx = x_p; su = u_p; sm = m_p;
        p00 = n00; p01 = n01; p02 = n02; p11 = n11; p12 = n12; p22 = n22;
    };

    auto update = [&](float y) {
        float innov = y - sx;
        float S    = p00 + Rn;
        float Sinv = __builtin_amdgcn_rcpf(S);
        float K0 = p00 * Sinv, K1 = p01 * Sinv, K2 = p02 * Sinv;
        sx += K0 * innov; su += K1 * innov; sm += K2 * innov;
        float a = 1.0f - K0;
        float n00 = a * a * p00 + Rn * K0 * K0;
        float n01 = a * (p01 - K1 * p00) + Rn * K0 * K1;
        float n02 = a * (p02 - K2 * p00) + Rn * K0 * K2;
        float n11 = S * K1 * K1 - 2.0f * K1 * p01 + p11;
        float n12 = S * K1 * K2 - K2 * p01 - K1 * p02 + p12;
        float n22 = S * K2 * K2 - 2.0f * K2 * p02 + p22;
        p00 = n00; p01 = n01; p02 = n02; p11 = n11; p12 = n12; p22 = n22;
    };

    const float4* v4  = (const float4*)(v_hist  + (size_t)b * LHIST);
    const float4* d4  = (const float4*)(dt_hist + (size_t)b * LHIST);
    const float4* y4  = (const float4*)(x_obs   + (size_t)b * LHIST);

    // ---- history: 8 chunks of 16 steps; double-buffered register staging ----
    // step t: v[t], dv = v[t]-v[t-1] (0 at t=0), dt = dt_hist[t+1], y = x_obs[t+1]
    float cv[CH], cd[CH], cy[CH];       // current chunk
    float nv[CH], nd[CH], ny[CH];       // prefetched next chunk

    auto load_chunk = [&](float (&vv)[CH], float (&dd)[CH], float (&yy)[CH], int k) {
        float4* V = (float4*)vv; float4* D = (float4*)dd; float4* Y = (float4*)yy;
        #pragma unroll
        for (int i = 0; i < CH / 4; ++i) {
            V[i] = v4[(CH / 4) * k + i];
            D[i] = d4[(CH / 4) * k + i];
            Y[i] = y4[(CH / 4) * k + i];
        }
    };

    load_chunk(cv, cd, cy, 0);
    load_chunk(nv, nd, ny, 1);

    // chunk 0: steps t = 0..14
    sx = cy[0];                                    // s0.x = x_obs[b][0]
    predict(cv[0], 0.0f, cd[1]); update(cy[1]);    // t = 0
    #pragma unroll
    for (int i = 1; i < CH - 1; ++i) {             // t = 1..14
        predict(cv[i], cv[i] - cv[i - 1], cd[i + 1]); update(cy[i + 1]);
    }
    float v_bridge  = cv[CH - 1];
    float dv_bridge = cv[CH - 1] - cv[CH - 2];

    // chunks 1..7: each covers t = 16k-1 .. 16k+14
    #pragma unroll 1
    for (int k = 1; k < LHIST / CH; ++k) {
        #pragma unroll
        for (int i = 0; i < CH; ++i) { cv[i] = nv[i]; cd[i] = nd[i]; cy[i] = ny[i]; }
        if (k < LHIST / CH - 1) load_chunk(nv, nd, ny, k + 1);   // prefetch ahead
        predict(v_bridge, dv_bridge, cd[0]); update(cy[0]);               // t=16k-1
        predict(cv[0], cv[0] - v_bridge, cd[1]); update(cy[1]);           // t=16k
        #pragma unroll
        for (int i = 1; i < CH - 1; ++i) {                                // t=16k+i
            predict(cv[i], cv[i] - cv[i - 1], cd[i + 1]); update(cy[i + 1]);
        }
        v_bridge  = cv[CH - 1];
        dv_bridge = cv[CH - 1] - cv[CH - 2];
    }
    // steps 0..126 done; v_bridge = v_hist[b][127]

    // ---- future inputs: loaded only now (not live across history) ----
    const float4* vf4 = (const float4*)(v_fut  + (size_t)b * HFUT);
    const float4* df4 = (const float4*)(dt_fut + (size_t)b * HFUT);
    float vf[HFUT], df[HFUT];
    {
        float4* VF = (float4*)vf; float4* DF = (float4*)df;
        #pragma unroll
        for (int i = 0; i < HFUT / 4; ++i) { VF[i] = vf4[i]; DF[i] = df4[i]; }
    }

    // ---- future rollout: 32 predicts, outputs staged in registers ----
    float oxp[HFUT], oxv[HFUT], oue[HFUT];
    float vp = v_bridge;
    #pragma unroll
    for (int j = 0; j < HFUT; ++j) {
        predict(vf[j], vf[j] - vp, df[j]);
        vp = vf[j];
        oxp[j] = sx; oxv[j] = p00; oue[j] = su;
    }

    // ---- back-to-back full-line burst stores (measured-ideal WRITE_SIZE) ----
    float4* xp = (float4*)(out + (size_t)b * HFUT);
    float4* xv = (float4*)(out + (size_t)BATCH * HFUT + (size_t)b * HFUT);
    float4* ue = (float4*)(out + 2 * (size_t)BATCH * HFUT + (size_t)b * HFUT);
    float4* OXP = (float4*)oxp; float4* OXV = (float4*)oxv; float4* OUE = (float4*)oue;
    #pragma unroll
    for (int i = 0; i < HFUT / 4; ++i) {
        xp[i] = OXP[i]; xv[i] = OXV[i]; ue[i] = OUE[i];
    }
}

extern "C" void kernel_launch(void* const* d_in, const int* in_sizes, int n_in,
                              void* d_out, int out_size, void* d_ws, size_t ws_size,
                              hipStream_t stream) {
    const float* v_hist  = (const float*)d_in[0];
    const float* dt_hist = (const float*)d_in[1];
    const float* x_obs   = (const float*)d_in[2];
    const float* v_fut   = (const float*)d_in[3];
    const float* dt_fut  = (const float*)d_in[4];
    const float* theta   = (const float*)d_in[5];
    float* out = (float*)d_out;

    dim3 grid(BATCH / 256), block(256);
    hipLaunchKernelGGL(kalman_fwd, grid, block, 0, stream,
                       v_hist, dt_hist, x_obs, v_fut, dt_fut, theta, out);
}